// Round 2
// baseline (316.942 us; speedup 1.0000x reference)
//
#include <hip/hip_runtime.h>
#include <math.h>

#define B_N   32768
#define D_N   128
#define HIST_N 30
#define M_N   15
#define H_N   4

#define TILE_ROWS   256                       // rows per LDS tile
#define TILE_FLOATS (TILE_ROWS * HIST_N)      // 7680 floats = 30720 B
#define TILE_F4     (TILE_FLOATS / 4)         // 1920 float4
#define TILES_TOTAL (B_N * D_N / TILE_ROWS)   // 16384
#define FWD_BLOCKS  2048
#define TILES_PER_BLOCK (TILES_TOTAL / FWD_BLOCKS)  // 8

// ---------------------------------------------------------------------------
// Kernel 1: compute W2 (4x128) and W3 (4x128) from the tiny parameter math.
// W' = a * (U diag(ratio) U^T) W + r * W, ratio_i = (softplus(sc_i)*S_i+sh_i)/S_i
// where G = W W^T = U diag(S^2) U^T  (4x4 symmetric eigenproblem, f64 Jacobi).
// ---------------------------------------------------------------------------
__global__ void prep_kernel(const float* __restrict__ w1,
                            const float* __restrict__ cw,
                            const float* __restrict__ sscale,
                            const float* __restrict__ sshift,
                            const float* __restrict__ alpha,
                            const float* __restrict__ rscale,
                            float* __restrict__ W2g,
                            float* __restrict__ W3g) {
    const int t = threadIdx.x;            // 0..127 = d
    __shared__ float  sw[M_N];
    __shared__ float  A[H_N][D_N];        // stage0 src (W1_c), stage1 dst (W3)
    __shared__ float  Bm[H_N][D_N];       // stage0 dst (W2),  stage1 src
    __shared__ double Gsh[H_N][H_N];
    __shared__ double Mm[H_N][H_N];

    if (t == 0) {
        float mx = cw[0];
        for (int m = 1; m < M_N; ++m) mx = fmaxf(mx, cw[m]);
        float s = 0.f;
        for (int m = 0; m < M_N; ++m) { float e = expf(cw[m] - mx); sw[m] = e; s += e; }
        float inv = 1.f / s;
        for (int m = 0; m < M_N; ++m) sw[m] *= inv;
    }
    __syncthreads();

    for (int h = 0; h < H_N; ++h) {
        float acc = 0.f;
        for (int m = 0; m < M_N; ++m)
            acc = fmaf(sw[m], w1[(m * H_N + h) * D_N + t], acc);
        A[h][t] = acc;
    }
    __syncthreads();

    const float a = alpha[0], r = rscale[0];

    for (int stage = 0; stage < 2; ++stage) {
        float (*src)[D_N] = (stage == 0) ? A : Bm;
        float (*dst)[D_N] = (stage == 0) ? Bm : A;

        if (t < 16) {
            int i = t >> 2, j = t & 3;
            double s = 0.0;
            for (int d = 0; d < D_N; ++d)
                s += (double)src[i][d] * (double)src[j][d];
            Gsh[i][j] = s;
        }
        __syncthreads();

        if (t == 0) {
            double G[4][4], U[4][4];
            for (int i = 0; i < 4; ++i)
                for (int j = 0; j < 4; ++j) { G[i][j] = Gsh[i][j]; U[i][j] = (i == j) ? 1.0 : 0.0; }
            for (int sweep = 0; sweep < 50; ++sweep) {
                double off = 0.0;
                for (int p = 0; p < 4; ++p)
                    for (int q = p + 1; q < 4; ++q) off += G[p][q] * G[p][q];
                if (off < 1e-28) break;
                for (int p = 0; p < 4; ++p)
                    for (int q = p + 1; q < 4; ++q) {
                        double apq = G[p][q];
                        if (fabs(apq) < 1e-300) continue;
                        double theta = (G[q][q] - G[p][p]) / (2.0 * apq);
                        double tt = ((theta >= 0.0) ? 1.0 : -1.0) /
                                    (fabs(theta) + sqrt(theta * theta + 1.0));
                        double c = 1.0 / sqrt(tt * tt + 1.0), sn = tt * c;
                        for (int i = 0; i < 4; ++i) {
                            double gip = G[i][p], giq = G[i][q];
                            G[i][p] = c * gip - sn * giq;
                            G[i][q] = sn * gip + c * giq;
                        }
                        for (int i = 0; i < 4; ++i) {
                            double gpi = G[p][i], gqi = G[q][i];
                            G[p][i] = c * gpi - sn * gqi;
                            G[q][i] = sn * gpi + c * gqi;
                        }
                        for (int i = 0; i < 4; ++i) {
                            double uip = U[i][p], uiq = U[i][q];
                            U[i][p] = c * uip - sn * uiq;
                            U[i][q] = sn * uip + c * uiq;
                        }
                    }
            }
            int ord[4] = {0, 1, 2, 3};
            for (int i = 0; i < 4; ++i)
                for (int j = i + 1; j < 4; ++j)
                    if (G[ord[j]][ord[j]] > G[ord[i]][ord[i]]) { int tmp = ord[i]; ord[i] = ord[j]; ord[j] = tmp; }
            double ratio[4];
            for (int i = 0; i < 4; ++i) {
                double ev = G[ord[i]][ord[i]];
                double S = sqrt(fmax(ev, 0.0));
                double x = (double)sscale[i];
                double sp = (x > 20.0) ? x : log1p(exp(x));
                double Snew = sp * S + (double)sshift[i];
                ratio[i] = (S > 1e-300) ? (Snew / S) : sp;
            }
            for (int i = 0; i < 4; ++i)
                for (int j = 0; j < 4; ++j) {
                    double s = 0.0;
                    for (int k = 0; k < 4; ++k)
                        s += U[i][ord[k]] * ratio[k] * U[j][ord[k]];
                    Mm[i][j] = s;
                }
        }
        __syncthreads();

        for (int h = 0; h < H_N; ++h) {
            double s = 0.0;
            for (int k = 0; k < H_N; ++k) s += Mm[h][k] * (double)src[k][t];
            dst[h][t] = (float)((double)a * s + (double)r * (double)src[h][t]);
        }
        __syncthreads();
    }

    for (int h = 0; h < H_N; ++h) {
        W2g[h * D_N + t] = Bm[h][t];   // W2[h][d]
        W3g[h * D_N + t] = A[h][t];    // W3[h][d]
    }
}

// ---------------------------------------------------------------------------
// Kernel 2: streaming bulk with coalesced LDS staging.
// Each block owns 8 consecutive tiles of 256 rows. Per tile: dense float4
// loads of the whole 30720B tile into registers (issued BEFORE the barrier so
// they overlap the previous tile's compute), reg->LDS, barrier, then each
// thread reads its row's last 15 floats from LDS and does the 2-layer math.
// d = tid & 127 is constant per thread, so the 77 per-d params live in regs.
// ---------------------------------------------------------------------------
__global__ __launch_bounds__(256) void fwd_kernel(
        const float* __restrict__ pa,
        const float* __restrict__ w1,
        const float* __restrict__ b1,
        const float* __restrict__ b2,
        const float* __restrict__ b3,
        const float* __restrict__ W2g,
        const float* __restrict__ W3g,
        float* __restrict__ out) {
    const int tid = threadIdx.x;
    const int d = tid & 127;

    __shared__ float4 lds4[TILE_F4];
    float* lds = (float*)lds4;

    // hoist per-d parameters into registers (fully static indexing)
    float wv[M_N][H_N];
#pragma unroll
    for (int m = 0; m < M_N; ++m)
#pragma unroll
        for (int h = 0; h < H_N; ++h)
            wv[m][h] = w1[(m * H_N + h) * D_N + d];

    float b1v[H_N], b2v[H_N], w2v[H_N], w3v[H_N];
#pragma unroll
    for (int h = 0; h < H_N; ++h) {
        b1v[h] = b1[h * D_N + d];
        b2v[h] = b2[h * D_N + d];
        w2v[h] = W2g[h * D_N + d];
        w3v[h] = W3g[h * D_N + d];
    }
    const float b3v = b3[d];

    const float4* pa4 = (const float4*)pa;

    for (int k = 0; k < TILES_PER_BLOCK; ++k) {
        const size_t t = (size_t)blockIdx.x * TILES_PER_BLOCK + k;
        const float4* src = pa4 + t * TILE_F4;

        // issue next tile's loads before waiting on previous compute
        float4 r[8];
#pragma unroll
        for (int j = 0; j < 7; ++j) r[j] = src[j * 256 + tid];
        if (tid < 128) r[7] = src[7 * 256 + tid];

        if (k > 0) __syncthreads();   // previous tile's LDS reads done
#pragma unroll
        for (int j = 0; j < 7; ++j) lds4[j * 256 + tid] = r[j];
        if (tid < 128) lds4[7 * 256 + tid] = r[7];
        __syncthreads();

        float x[M_N];
#pragma unroll
        for (int m = 0; m < M_N; ++m)
            x[m] = lds[tid * HIST_N + (HIST_N - M_N) + m];

        float h1[H_N] = {0.f, 0.f, 0.f, 0.f};
#pragma unroll
        for (int m = 0; m < M_N; ++m)
#pragma unroll
            for (int h = 0; h < H_N; ++h)
                h1[h] = fmaf(x[m], wv[m][h], h1[h]);

        float acc = b3v;
#pragma unroll
        for (int h = 0; h < H_N; ++h) {
            float v = fmaxf(h1[h] + b1v[h], 0.f);
            float u = fmaxf(fmaf(v, w2v[h], b2v[h]), 0.f);
            acc = fmaf(u, w3v[h], acc);
        }
        out[t * TILE_ROWS + tid] = acc;
    }
}

extern "C" void kernel_launch(void* const* d_in, const int* in_sizes, int n_in,
                              void* d_out, int out_size, void* d_ws, size_t ws_size,
                              hipStream_t stream) {
    const float* pa = (const float*)d_in[0];   // (B, D, HIST)
    const float* w1 = (const float*)d_in[1];   // (M, H, D)
    const float* b1 = (const float*)d_in[2];   // (1, H, D)
    const float* b2 = (const float*)d_in[3];   // (1, H, D)
    const float* b3 = (const float*)d_in[4];   // (1, D)
    const float* cw = (const float*)d_in[5];   // (M,)
    const float* ss = (const float*)d_in[6];   // (RANK,)
    const float* sh = (const float*)d_in[7];   // (RANK,)
    const float* al = (const float*)d_in[8];   // (1,)
    const float* rs = (const float*)d_in[9];   // (1,)
    float* out = (float*)d_out;                // (B, D) f32

    float* W2g = (float*)d_ws;                 // 4*128 floats
    float* W3g = W2g + H_N * D_N;              // 4*128 floats

    prep_kernel<<<1, 128, 0, stream>>>(w1, cw, ss, sh, al, rs, W2g, W3g);
    fwd_kernel<<<FWD_BLOCKS, 256, 0, stream>>>(pa, w1, b1, b2, b3, W2g, W3g, out);
}

// Round 4
// 138.131 us; speedup vs baseline: 2.2945x; 2.2945x over previous
//
#include <hip/hip_runtime.h>
#include <math.h>

#define B_N   32768
#define D_N   128
#define HIST_N 30
#define M_N   15
#define H_N   4

#define TILE_ROWS   256                         // rows per LDS tile
#define TILE_BYTES  (TILE_ROWS * HIST_N * 4)    // 30720 B
#define TILE_FLOATS (TILE_ROWS * HIST_N)        // 7680 floats
#define WAVE_BYTES  (TILE_BYTES / 4)            // 7680 B per wave
#define WAVE_FLOATS (WAVE_BYTES / 4)            // 1920 floats
#define CALLS_PER_WAVE 30                       // 30 x 256B (64 lanes x 4B)
#define TILES_TOTAL (B_N * D_N / TILE_ROWS)     // 16384
#define FWD_BLOCKS  2048
#define TILES_PER_BLOCK (TILES_TOTAL / FWD_BLOCKS)  // 8

// async global -> LDS, 4 bytes per lane (global_load_lds_dword) — the
// HW-verified size (learn_hip m03). LDS dest = wave-uniform base + lane*4.
__device__ __forceinline__ void gload4(const void* g, float* l) {
    __builtin_amdgcn_global_load_lds(
        (const __attribute__((address_space(1))) unsigned int*)g,
        (__attribute__((address_space(3))) unsigned int*)l,
        4, 0, 0);
}

// ---------------------------------------------------------------------------
// Kernel 1: tiny parameter math -> W2 (4x128), W3 (4x128).
// W' = a * (U diag(ratio) U^T) W + r * W, ratio_i = (softplus(sc_i)*S_i+sh_i)/S_i
// with G = W W^T = U diag(S^2) U^T (4x4 symmetric eigenproblem, f64 Jacobi).
// ---------------------------------------------------------------------------
__global__ void prep_kernel(const float* __restrict__ w1,
                            const float* __restrict__ cw,
                            const float* __restrict__ sscale,
                            const float* __restrict__ sshift,
                            const float* __restrict__ alpha,
                            const float* __restrict__ rscale,
                            float* __restrict__ W2g,
                            float* __restrict__ W3g) {
    const int t = threadIdx.x;            // 0..127 = d
    __shared__ float  sw[M_N];
    __shared__ float  A[H_N][D_N];
    __shared__ float  Bm[H_N][D_N];
    __shared__ double Gsh[H_N][H_N];
    __shared__ double Mm[H_N][H_N];

    if (t == 0) {
        float mx = cw[0];
        for (int m = 1; m < M_N; ++m) mx = fmaxf(mx, cw[m]);
        float s = 0.f;
        for (int m = 0; m < M_N; ++m) { float e = expf(cw[m] - mx); sw[m] = e; s += e; }
        float inv = 1.f / s;
        for (int m = 0; m < M_N; ++m) sw[m] *= inv;
    }
    __syncthreads();

    for (int h = 0; h < H_N; ++h) {
        float acc = 0.f;
        for (int m = 0; m < M_N; ++m)
            acc = fmaf(sw[m], w1[(m * H_N + h) * D_N + t], acc);
        A[h][t] = acc;
    }
    __syncthreads();

    const float a = alpha[0], r = rscale[0];

    for (int stage = 0; stage < 2; ++stage) {
        float (*src)[D_N] = (stage == 0) ? A : Bm;
        float (*dst)[D_N] = (stage == 0) ? Bm : A;

        if (t < 16) {
            int i = t >> 2, j = t & 3;
            double s = 0.0;
            for (int dd = 0; dd < D_N; ++dd)
                s += (double)src[i][dd] * (double)src[j][dd];
            Gsh[i][j] = s;
        }
        __syncthreads();

        if (t == 0) {
            double G[4][4], U[4][4];
            for (int i = 0; i < 4; ++i)
                for (int j = 0; j < 4; ++j) { G[i][j] = Gsh[i][j]; U[i][j] = (i == j) ? 1.0 : 0.0; }
            for (int sweep = 0; sweep < 50; ++sweep) {
                double off = 0.0;
                for (int p = 0; p < 4; ++p)
                    for (int q = p + 1; q < 4; ++q) off += G[p][q] * G[p][q];
                if (off < 1e-28) break;
                for (int p = 0; p < 4; ++p)
                    for (int q = p + 1; q < 4; ++q) {
                        double apq = G[p][q];
                        if (fabs(apq) < 1e-300) continue;
                        double theta = (G[q][q] - G[p][p]) / (2.0 * apq);
                        double tt = ((theta >= 0.0) ? 1.0 : -1.0) /
                                    (fabs(theta) + sqrt(theta * theta + 1.0));
                        double c = 1.0 / sqrt(tt * tt + 1.0), sn = tt * c;
                        for (int i = 0; i < 4; ++i) {
                            double gip = G[i][p], giq = G[i][q];
                            G[i][p] = c * gip - sn * giq;
                            G[i][q] = sn * gip + c * giq;
                        }
                        for (int i = 0; i < 4; ++i) {
                            double gpi = G[p][i], gqi = G[q][i];
                            G[p][i] = c * gpi - sn * gqi;
                            G[q][i] = sn * gpi + c * gqi;
                        }
                        for (int i = 0; i < 4; ++i) {
                            double uip = U[i][p], uiq = U[i][q];
                            U[i][p] = c * uip - sn * uiq;
                            U[i][q] = sn * uip + c * uiq;
                        }
                    }
            }
            int ord[4] = {0, 1, 2, 3};
            for (int i = 0; i < 4; ++i)
                for (int j = i + 1; j < 4; ++j)
                    if (G[ord[j]][ord[j]] > G[ord[i]][ord[i]]) { int tmp = ord[i]; ord[i] = ord[j]; ord[j] = tmp; }
            double ratio[4];
            for (int i = 0; i < 4; ++i) {
                double ev = G[ord[i]][ord[i]];
                double S = sqrt(fmax(ev, 0.0));
                double x = (double)sscale[i];
                double sp = (x > 20.0) ? x : log1p(exp(x));
                double Snew = sp * S + (double)sshift[i];
                ratio[i] = (S > 1e-300) ? (Snew / S) : sp;
            }
            for (int i = 0; i < 4; ++i)
                for (int j = 0; j < 4; ++j) {
                    double s = 0.0;
                    for (int kk = 0; kk < 4; ++kk)
                        s += U[i][ord[kk]] * ratio[kk] * U[j][ord[kk]];
                    Mm[i][j] = s;
                }
        }
        __syncthreads();

        for (int h = 0; h < H_N; ++h) {
            double s = 0.0;
            for (int kk = 0; kk < H_N; ++kk) s += Mm[h][kk] * (double)src[kk][t];
            dst[h][t] = (float)((double)a * s + (double)r * (double)src[h][t]);
        }
        __syncthreads();
    }

    for (int h = 0; h < H_N; ++h) {
        W2g[h * D_N + t] = Bm[h][t];   // W2[h][d]
        W3g[h * D_N + t] = A[h][t];    // W3[h][d]
    }
}

// ---------------------------------------------------------------------------
// Kernel 2: streaming bulk. Per-wave software pipeline, NO barriers:
// each wave stages exactly the 1920-float LDS region its own 64 threads read
// (64 rows x 30 floats), so all hazards are intra-wave and handled by the
// counted vmcnt. Double-buffered: issue tile k+1's 30 dword-DMA loads, then
// s_waitcnt vmcnt(30) drains exactly tile k (+ the prior out-store), leaving
// tile k+1 in flight under tile k's compute.
// ---------------------------------------------------------------------------
__global__ __launch_bounds__(256, 2) void fwd_kernel(
        const float* __restrict__ pa,
        const float* __restrict__ w1,
        const float* __restrict__ b1,
        const float* __restrict__ b2,
        const float* __restrict__ b3,
        const float* __restrict__ W2g,
        const float* __restrict__ W3g,
        float* __restrict__ out) {
    const int tid   = threadIdx.x;
    const int lane  = tid & 63;
    const int wv_id = tid >> 6;           // wave 0..3
    const int d     = tid & 127;

    __shared__ float lds[2][TILE_FLOATS];   // 2 x 30720 B = 61440 B

    // hoist per-d parameters into registers (static indexing only)
    float wv[M_N][H_N];
#pragma unroll
    for (int m = 0; m < M_N; ++m)
#pragma unroll
        for (int h = 0; h < H_N; ++h)
            wv[m][h] = w1[(m * H_N + h) * D_N + d];

    float b1v[H_N], b2v[H_N], w2v[H_N], w3v[H_N];
#pragma unroll
    for (int h = 0; h < H_N; ++h) {
        b1v[h] = b1[h * D_N + d];
        b2v[h] = b2[h * D_N + d];
        w2v[h] = W2g[h * D_N + d];
        w3v[h] = W3g[h * D_N + d];
    }
    const float b3v = b3[d];

    const char* pab = (const char*)pa;
    const size_t tile0 = (size_t)blockIdx.x * TILES_PER_BLOCK;

    // issue one tile's staging: this wave's 7680B as 30 x 256B dword-DMAs
    auto issue_tile = [&](size_t t, int buf) {
        const char* g = pab + t * TILE_BYTES + wv_id * WAVE_BYTES + (size_t)lane * 4;
        float* l = &lds[buf][0] + wv_id * WAVE_FLOATS;
#pragma unroll
        for (int c = 0; c < CALLS_PER_WAVE; ++c)
            gload4(g + c * 256, l + c * 64);
    };

    issue_tile(tile0, 0);   // prologue: tile 0 in flight

    for (int k = 0; k < TILES_PER_BLOCK; ++k) {
        if (k + 1 < TILES_PER_BLOCK) {
            issue_tile(tile0 + k + 1, (k + 1) & 1);
            // drain tile k's 30 loads (+prior store); keep tile k+1 in flight
            asm volatile("s_waitcnt vmcnt(30)" ::: "memory");
        } else {
            asm volatile("s_waitcnt vmcnt(0)" ::: "memory");
        }

        const float* L = &lds[k & 1][0] + tid * HIST_N + (HIST_N - M_N);
        float x[M_N];
#pragma unroll
        for (int m = 0; m < M_N; ++m) x[m] = L[m];

        float h1[H_N] = {0.f, 0.f, 0.f, 0.f};
#pragma unroll
        for (int m = 0; m < M_N; ++m)
#pragma unroll
            for (int h = 0; h < H_N; ++h)
                h1[h] = fmaf(x[m], wv[m][h], h1[h]);

        float acc = b3v;
#pragma unroll
        for (int h = 0; h < H_N; ++h) {
            float v = fmaxf(h1[h] + b1v[h], 0.f);
            float u = fmaxf(fmaf(v, w2v[h], b2v[h]), 0.f);
            acc = fmaf(u, w3v[h], acc);
        }
        out[(tile0 + k) * TILE_ROWS + tid] = acc;
    }
}

extern "C" void kernel_launch(void* const* d_in, const int* in_sizes, int n_in,
                              void* d_out, int out_size, void* d_ws, size_t ws_size,
                              hipStream_t stream) {
    const float* pa = (const float*)d_in[0];   // (B, D, HIST)
    const float* w1 = (const float*)d_in[1];   // (M, H, D)
    const float* b1 = (const float*)d_in[2];   // (1, H, D)
    const float* b2 = (const float*)d_in[3];   // (1, H, D)
    const float* b3 = (const float*)d_in[4];   // (1, D)
    const float* cw = (const float*)d_in[5];   // (M,)
    const float* ss = (const float*)d_in[6];   // (RANK,)
    const float* sh = (const float*)d_in[7];   // (RANK,)
    const float* al = (const float*)d_in[8];   // (1,)
    const float* rs = (const float*)d_in[9];   // (1,)
    float* out = (float*)d_out;                // (B, D) f32

    float* W2g = (float*)d_ws;                 // 4*128 floats
    float* W3g = W2g + H_N * D_N;              // 4*128 floats

    prep_kernel<<<1, 128, 0, stream>>>(w1, cw, ss, sh, al, rs, W2g, W3g);
    fwd_kernel<<<FWD_BLOCKS, 256, 0, stream>>>(pa, w1, b1, b2, b3, W2g, W3g, out);
}

// Round 5
// 121.720 us; speedup vs baseline: 2.6039x; 1.1348x over previous
//
#include <hip/hip_runtime.h>
#include <math.h>

#define B_N    32768
#define D_N    128
#define HIST_N 30
#define M_N    15
#define H_N    4

#define TILE_ROWS   256
#define TILE_FLOATS (TILE_ROWS * HIST_N)          // 7680 floats
#define TILE_BYTES  (TILE_FLOATS * 4)             // 30720 B
#define WAVE_FLOATS (TILE_FLOATS / 4)             // 1920 floats per wave
#define WAVE_BYTES  (WAVE_FLOATS * 4)             // 7680 B per wave
#define NBLOCKS     512                           // 2 resident blocks per CU
#define TPB         (B_N * D_N / TILE_ROWS / NBLOCKS)  // 32 tiles per block
// per-wave DMA calls per tile: 7 x 16B-lane + 2 x 4B-lane = 9 loads = 7680 B
#define LOADS_PER_TILE 9

__device__ __forceinline__ void gload16(const void* g, float* l) {
    __builtin_amdgcn_global_load_lds(
        (const __attribute__((address_space(1))) unsigned int*)g,
        (__attribute__((address_space(3))) unsigned int*)l, 16, 0, 0);
}
__device__ __forceinline__ void gload4(const void* g, float* l) {
    __builtin_amdgcn_global_load_lds(
        (const __attribute__((address_space(1))) unsigned int*)g,
        (__attribute__((address_space(3))) unsigned int*)l, 4, 0, 0);
}

// ---------------------------------------------------------------------------
// Single fused persistent kernel.
// Param math (once per block, overlapped with first tiles' DMA):
//   sw = softmax(cw); W1c = sum_m sw_m * W1[m]          (threads, LDS)
//   G = W1c W1c^T = U diag(lam) U^T                     (f32 Jacobi, thread 0)
//   Shared-eigenvector identity: spec(spec(W)) reuses U:
//     c1_e = a*ratio1_e + r ; S2_e = c1_e * S1_e ; c2 from |S2| re-sorted
//     M2 = U diag(c1) U^T ; M3 = U diag(c1*c2) U^T
//   w2v[h] = (M2 W1c)[h][d] ; w3v[h] = (M3 W1c)[h][d]   (per-thread regs)
// Main loop (per-wave pipeline, no barriers, counted vmcnt):
//   prologue T0,T1; iter k: wait vmcnt(9) -> compute T_k -> store
//   -> issue T_{k+2} into freed buffer.
// ---------------------------------------------------------------------------
__global__ __launch_bounds__(256, 2) void fused_kernel(
        const float* __restrict__ pa,
        const float* __restrict__ w1,
        const float* __restrict__ b1,
        const float* __restrict__ b2,
        const float* __restrict__ b3,
        const float* __restrict__ cw,
        const float* __restrict__ ss,
        const float* __restrict__ sh,
        const float* __restrict__ al,
        const float* __restrict__ rs,
        float* __restrict__ out) {
    const int tid   = threadIdx.x;
    const int lane  = tid & 63;
    const int wv_id = tid >> 6;          // wave 0..3
    const int d     = tid & 127;

    __shared__ __align__(16) float lds[2][TILE_FLOATS];   // 61440 B
    __shared__ float W1c[H_N][D_N];                       // 2048 B
    __shared__ float Gsh[16];
    __shared__ float Msh[32];                             // M2[16], M3[16]

    const char* pab = (const char*)pa;
    const size_t tile0 = (size_t)blockIdx.x * TPB;

    auto issue_tile = [&](size_t t, int buf) {
        const char* gw = pab + t * TILE_BYTES + (size_t)wv_id * WAVE_BYTES;
        float* lw = &lds[buf][0] + wv_id * WAVE_FLOATS;
#pragma unroll
        for (int c = 0; c < 7; ++c)
            gload16(gw + c * 1024 + lane * 16, lw + c * 256);
#pragma unroll
        for (int c = 0; c < 2; ++c)
            gload4(gw + 7168 + c * 256 + lane * 4, lw + 1792 + c * 64);
    };

    // prologue: two tiles in flight before anything else
    issue_tile(tile0, 0);
    issue_tile(tile0 + 1, 1);

    // ---- per-d parameter loads (regular VMEM, overlap the DMAs) ----
    float wv[M_N][H_N];
#pragma unroll
    for (int m = 0; m < M_N; ++m)
#pragma unroll
        for (int h = 0; h < H_N; ++h)
            wv[m][h] = w1[(m * H_N + h) * D_N + d];

    float b1v[H_N], b2v[H_N];
#pragma unroll
    for (int h = 0; h < H_N; ++h) {
        b1v[h] = b1[h * D_N + d];
        b2v[h] = b2[h * D_N + d];
    }
    const float b3v = b3[d];

    // ---- softmax(cw), redundant per-thread (uniform -> scalar loads) ----
    float swm[M_N];
    {
        float mx = cw[0];
#pragma unroll
        for (int m = 1; m < M_N; ++m) mx = fmaxf(mx, cw[m]);
        float s = 0.f;
#pragma unroll
        for (int m = 0; m < M_N; ++m) { swm[m] = expf(cw[m] - mx); s += swm[m]; }
        float inv = 1.f / s;
#pragma unroll
        for (int m = 0; m < M_N; ++m) swm[m] *= inv;
    }

    // ---- W1c into LDS (threads 0..127 own d=tid) ----
    if (tid < 128) {
#pragma unroll
        for (int h = 0; h < H_N; ++h) {
            float acc = 0.f;
#pragma unroll
            for (int m = 0; m < M_N; ++m) acc = fmaf(swm[m], wv[m][h], acc);
            W1c[h][tid] = acc;
        }
    }
    asm volatile("s_waitcnt lgkmcnt(0)" ::: "memory");
    __builtin_amdgcn_s_barrier();

    // ---- Gram (16 threads, staggered to avoid bank conflicts) ----
    if (tid < 16) {
        const int i = tid >> 2, j = tid & 3;
        float s = 0.f;
        for (int st = 0; st < 128; ++st) {
            int dd = (st + tid * 8) & 127;
            s = fmaf(W1c[i][dd], W1c[j][dd], s);
        }
        Gsh[tid] = s;
    }
    asm volatile("s_waitcnt lgkmcnt(0)" ::: "memory");
    __builtin_amdgcn_s_barrier();

    // ---- thread 0: Jacobi + two-stage spectral scalars -> M2, M3 ----
    if (tid == 0) {
        float G[4][4], U[4][4];
#pragma unroll
        for (int i = 0; i < 4; ++i)
#pragma unroll
            for (int j = 0; j < 4; ++j) {
                G[i][j] = Gsh[i * 4 + j];
                U[i][j] = (i == j) ? 1.f : 0.f;
            }
        for (int sweep = 0; sweep < 6; ++sweep)
            for (int p = 0; p < 3; ++p)
                for (int q = p + 1; q < 4; ++q) {
                    float apq = G[p][q];
                    if (fabsf(apq) < 1e-30f) continue;
                    float theta = (G[q][q] - G[p][p]) / (2.f * apq);
                    float t = ((theta >= 0.f) ? 1.f : -1.f) /
                              (fabsf(theta) + sqrtf(theta * theta + 1.f));
                    float c = 1.f / sqrtf(t * t + 1.f), sn = t * c;
                    for (int i = 0; i < 4; ++i) {
                        float gip = G[i][p], giq = G[i][q];
                        G[i][p] = c * gip - sn * giq;
                        G[i][q] = sn * gip + c * giq;
                    }
                    for (int i = 0; i < 4; ++i) {
                        float gpi = G[p][i], gqi = G[q][i];
                        G[p][i] = c * gpi - sn * gqi;
                        G[q][i] = sn * gpi + c * gqi;
                    }
                    for (int i = 0; i < 4; ++i) {
                        float uip = U[i][p], uiq = U[i][q];
                        U[i][p] = c * uip - sn * uiq;
                        U[i][q] = sn * uip + c * uiq;
                    }
                }
        float lam[4];
#pragma unroll
        for (int i = 0; i < 4; ++i) lam[i] = G[i][i];
        int ord[4] = {0, 1, 2, 3};
        for (int i = 0; i < 4; ++i)
            for (int j = i + 1; j < 4; ++j)
                if (lam[ord[j]] > lam[ord[i]]) { int t2 = ord[i]; ord[i] = ord[j]; ord[j] = t2; }

        const float a = al[0], r = rs[0];
        float c1[4], S2a[4];
        for (int p = 0; p < 4; ++p) {
            int e = ord[p];
            float S = sqrtf(fmaxf(lam[e], 0.f));
            float x = ss[p];
            float sp = (x > 20.f) ? x : log1pf(expf(x));
            float ratio = (S > 1e-30f) ? ((sp * S + sh[p]) / S) : sp;
            c1[e] = a * ratio + r;
            S2a[e] = fabsf(c1[e]) * S;      // |singular values| of W2
        }
        int ord2[4] = {0, 1, 2, 3};
        for (int i = 0; i < 4; ++i)
            for (int j = i + 1; j < 4; ++j)
                if (S2a[ord2[j]] > S2a[ord2[i]]) { int t2 = ord2[i]; ord2[i] = ord2[j]; ord2[j] = t2; }
        float c12[4];
        for (int p = 0; p < 4; ++p) {
            int e = ord2[p];
            float Sa = S2a[e];
            float x = ss[p];
            float sp = (x > 20.f) ? x : log1pf(expf(x));
            float ratio2 = (Sa > 1e-30f) ? ((sp * Sa + sh[p]) / Sa) : sp;
            c12[e] = (a * ratio2 + r) * c1[e];
        }
#pragma unroll
        for (int i = 0; i < 4; ++i)
#pragma unroll
            for (int j = 0; j < 4; ++j) {
                float m2 = 0.f, m3 = 0.f;
#pragma unroll
                for (int e = 0; e < 4; ++e) {
                    float uu = U[i][e] * U[j][e];
                    m2 = fmaf(uu, c1[e], m2);
                    m3 = fmaf(uu, c12[e], m3);
                }
                Msh[i * 4 + j] = m2;
                Msh[16 + i * 4 + j] = m3;
            }
    }
    asm volatile("s_waitcnt lgkmcnt(0)" ::: "memory");
    __builtin_amdgcn_s_barrier();

    // ---- per-thread W2/W3 columns ----
    float w2v[H_N], w3v[H_N];
#pragma unroll
    for (int h = 0; h < H_N; ++h) {
        float s2 = 0.f, s3 = 0.f;
#pragma unroll
        for (int k4 = 0; k4 < 4; ++k4) {
            float wc = W1c[k4][d];
            s2 = fmaf(Msh[h * 4 + k4], wc, s2);
            s3 = fmaf(Msh[16 + h * 4 + k4], wc, s3);
        }
        w2v[h] = s2;
        w3v[h] = s3;
    }

    // ---- main streaming loop: per-wave counted-vmcnt pipeline ----
#pragma unroll 2
    for (int k = 0; k < TPB; ++k) {
        if (k == TPB - 1)
            asm volatile("s_waitcnt vmcnt(0)" ::: "memory");
        else
            asm volatile("s_waitcnt vmcnt(9)" ::: "memory");   // = LOADS_PER_TILE

        const float* L = &lds[k & 1][0] + tid * HIST_N + (HIST_N - M_N);
        float x0 = L[0];
        float h1[H_N];
#pragma unroll
        for (int h = 0; h < H_N; ++h) h1[h] = x0 * wv[0][h];
#pragma unroll
        for (int c = 0; c < 7; ++c) {
            float2 q = *(const float2*)(L + 1 + 2 * c);   // 8B-aligned
#pragma unroll
            for (int h = 0; h < H_N; ++h) h1[h] = fmaf(q.x, wv[1 + 2 * c][h], h1[h]);
#pragma unroll
            for (int h = 0; h < H_N; ++h) h1[h] = fmaf(q.y, wv[2 + 2 * c][h], h1[h]);
        }
        float acc = b3v;
#pragma unroll
        for (int h = 0; h < H_N; ++h) {
            float v = fmaxf(h1[h] + b1v[h], 0.f);
            float u = fmaxf(fmaf(v, w2v[h], b2v[h]), 0.f);
            acc = fmaf(u, w3v[h], acc);
        }
        out[(tile0 + k) * TILE_ROWS + tid] = acc;

        asm volatile("" ::: "memory");   // pin reads/store before next DMA issue
        if (k + 2 < TPB) issue_tile(tile0 + k + 2, k & 1);
    }
}

extern "C" void kernel_launch(void* const* d_in, const int* in_sizes, int n_in,
                              void* d_out, int out_size, void* d_ws, size_t ws_size,
                              hipStream_t stream) {
    const float* pa = (const float*)d_in[0];   // (B, D, HIST)
    const float* w1 = (const float*)d_in[1];   // (M, H, D)
    const float* b1 = (const float*)d_in[2];   // (1, H, D)
    const float* b2 = (const float*)d_in[3];   // (1, H, D)
    const float* b3 = (const float*)d_in[4];   // (1, D)
    const float* cw = (const float*)d_in[5];   // (M,)
    const float* ss = (const float*)d_in[6];   // (RANK,)
    const float* sh = (const float*)d_in[7];   // (RANK,)
    const float* al = (const float*)d_in[8];   // (1,)
    const float* rs = (const float*)d_in[9];   // (1,)
    float* out = (float*)d_out;                // (B, D) f32

    fused_kernel<<<NBLOCKS, 256, 0, stream>>>(pa, w1, b1, b2, b3, cw, ss, sh, al, rs, out);
}